// Round 7
// baseline (293.441 us; speedup 1.0000x reference)
//
#include <hip/hip_runtime.h>

// Problem: BATCH=64, NFILT=512, T=1024, FFT over first 512 samples, 257 bins.
//   bc = (fc/Q)*0.5*sqrt(2pi)/FS ; n = t+1
//   y[b,f,t] = exp(-(bc*n)^2) * cos(2pi*fc/FS*n)
//   maxsq[f] = max_{b,k} |DFT_512(y[b,f,0:512])[k]|^2
//   out[b,f,t] = y[b,f,1023-t] * rsqrt(maxsq[f])
//
// R17: MEASUREMENT ROUND #2 (output bit-identical to R12).
//   R16 verdict: write path is PERFECT — 8x replica ran at 7.9 TB/s = 98%
//   of spec peak, w = 17.05us/rep. But calibrations conflict on k_maxfft:
//   R13-derived C=99.7 => m ~= 32us; bottom-up + R15-consistency => C~122-134,
//   m ~= 10us. The two imply different Round-7 designs (attack k_maxfft vs
//   overlap-only, floor C+17). This round replicates k_maxfft 8x (same
//   rotation trick: rep r handles sig+r*4096, bijection => every rep writes
//   every ws entry with its exact R12 value; idempotent) + exact R12 k_write.
//   Discriminating predictions:
//     m~=32  =>  probe ~256us (top-1), total ~370-395us.
//     m~=10  =>  probe ~80-90us,       total ~220-235us.
//   Probe counters (VALUBusy/Occupancy/FETCH_SIZE/LDS_CONFLICT) then
//   diagnose k_maxfft's gap-vs-model if one exists.

#define BCOEF_K 7.8332133582218756e-05f  // 0.5*sqrt(2*pi)/16000
#define INV_FS  6.25e-05f                // 1/16000
#define TWO_PI  6.28318530717958647692f
#define PI_F    3.14159265358979323846f
#define SIGK_K  115.2309f                // sqrt(2)*512/(2*pi)
#define KAPPA   1.3f                     // pruning safety factor
#define FULL_FC 700.0f                   // below this fc, evaluate all 64 b

typedef float vf4 __attribute__((ext_vector_type(4)));

__device__ __forceinline__ float fast_carrier(float fcn, float n) {
  float rev = fcn * n;
  float fr  = rev - floorf(rev);
  return __cosf(TWO_PI * fr);
}
__device__ __forceinline__ float fast_env(float x) { return __expf(-x * x); }

// ---------------------------------------------------------------------------
// Kernel 1 PROBE: exact R12 k_maxfft body, executed 8x with sig rotated by
// rep*4096 (bijection; every rep computes/stores the exact R12 value for its
// rotated signal => ws final state bit-identical to R12's). Long dispatch
// (8m) must enter rocprof top-5 => first direct counters for compute path.
// ---------------------------------------------------------------------------
__global__ __launch_bounds__(256) void k_maxfft_probe(const float* __restrict__ Q,
                                                      const float* __restrict__ fc,
                                                      float* __restrict__ ws) {
  const int tid  = threadIdx.x;
  const int w    = tid >> 6;           // wave 0..3
  const int lane = tid & 63;
  const int sig0 = blockIdx.x * 4 + w; // base bb*512 + f

  __shared__ __align__(16) float ybuf[4][512];
  float* const yw = &ybuf[w][0];
  const float4* const y4 = (const float4*)yw;

  for (int rep = 0; rep < 8; ++rep) {
    const int sig = (sig0 + rep * 4096) & 32767;  // bijection per rep
    const int f   = sig & 511;
    const int bb  = sig >> 9;

    const float fcv = fc[f];
    const float q   = Q[bb * 512 + f];
    const float bc  = (fcv / q) * BCOEF_K;
    const float fcn = fcv * INV_FS;

    // --- pruning: candidate iff bc <= KAPPA * bc_min(batch) or low-fc ---
    float qq = Q[lane * 512 + f];      // lane = batch index (L2-hot)
    #pragma unroll
    for (int d = 32; d > 0; d >>= 1) qq = fmaxf(qq, __shfl_xor(qq, d));
    if (fcv >= FULL_FC && bc * qq > KAPPA * fcv * BCOEF_K) {
      if (lane == 0) ws[f * 64 + bb] = 0.0f;   // provably below batch max
      continue;                                 // wave-uniform
    }

    // --- effective length: env < e^-16 beyond nstar = 4/bc ---
    const float nstar = 4.0f / bc;
    const int   N_eff = (nstar >= 510.0f) ? 512 : ((int)nstar + 2);
    const int   jmax  = (N_eff + 3) >> 2;      // float4 groups Goertzel reads
    const int   n4    = jmax << 2;             // samples to generate

    // prior rep's LDS reads must drain before overwrite (wave-local)
    asm volatile("s_waitcnt lgkmcnt(0)" ::: "memory");

    // --- lane-strided generation ---
    const int nit_g = (n4 + 63) >> 6;          // 1..8, wave-uniform
    for (int r = 0; r < nit_g; ++r) {
      const int idx = (r << 6) + lane;         // t index; n = idx+1
      const float n = (float)(idx + 1);
      const float v = fast_env(bc * n) * fast_carrier(fcn, n);
      if (idx < n4) yw[idx] = v;               // masked tail store
    }
    asm volatile("s_waitcnt lgkmcnt(0)" ::: "memory");

    // --- spectral-peak window (wave-uniform) ---
    const int kci  = (int)(fcn * 512.0f + 0.5f);
    const int W    = (int)(2.0f * (bc * SIGK_K)) + 6;
    const int k_lo = max(0, kci - W);
    const int k_hi = min(256, kci + W);
    const int nit  = ((k_hi - k_lo) >> 6) + 1;  // 1..5 iterations

    float mx = 0.0f;
    for (int it = 0; it < nit; ++it) {          // wave-uniform trip count
      const int   k = min(k_lo + (it << 6) + lane, k_hi);  // dup harmless
      const float c = 2.0f * cosf((float)k * (PI_F / 256.0f));
      float s1 = 0.0f, s2 = 0.0f;
      #pragma unroll 4
      for (int j = 0; j < jmax; ++j) {          // wave-uniform trip count
        const float4 x = y4[j];                 // wave-uniform broadcast
        float s;
        s = fmaf(c, s1, x.x - s2); s2 = s1; s1 = s;
        s = fmaf(c, s1, x.y - s2); s2 = s1; s1 = s;
        s = fmaf(c, s1, x.z - s2); s2 = s1; s1 = s;
        s = fmaf(c, s1, x.w - s2); s2 = s1; s1 = s;
      }
      mx = fmaxf(mx, fmaf(s1, s1, fmaf(s2, s2, -(c * s1 * s2))));
    }

    #pragma unroll
    for (int d = 32; d > 0; d >>= 1) mx = fmaxf(mx, __shfl_xor(mx, d));
    if (lane == 0) ws[f * 64 + bb] = mx;       // same value as R12
  }
}

// ---------------------------------------------------------------------------
// Kernel 2: EXACT R12 k_write (known 17.05us, 7.9 TB/s from R16 probe).
// ---------------------------------------------------------------------------
__global__ __launch_bounds__(256) void k_write(const float* __restrict__ Q,
                                               const float* __restrict__ fc,
                                               const float* __restrict__ ws,
                                               float* __restrict__ out) {
  const int tid  = threadIdx.x;
  const int w    = tid >> 6;            // wave = row within the 4-row block
  const int lane = tid & 63;
  const int sig  = blockIdx.x * 4 + w;  // bb*512 + f
  const int f    = sig & 511;
  const int bb   = sig >> 9;

  float mx = ws[f * 64 + lane];         // 64 consecutive floats, coalesced
  #pragma unroll
  for (int d = 32; d > 0; d >>= 1) mx = fmaxf(mx, __shfl_xor(mx, d));
  const float inv = rsqrtf(mx);

  const float fcv = fc[f];
  const float q   = Q[bb * 512 + f];
  const float bc  = (fcv / q) * BCOEF_K;
  const float fcn = fcv * INV_FS;
  const float nstar = 4.0f / bc;

  vf4* __restrict__ orow = (vf4*)out + (size_t)sig * 256;
  #pragma unroll
  for (int r = 0; r < 4; ++r) {
    const int qi = (r << 6) + lane;     // quad index within row, 0..255
    const int t0 = qi << 2;             // t of first element in quad
    vf4 v = {0.0f, 0.0f, 0.0f, 0.0f};
    // quad covers n = 1021-t0 .. 1024-t0; all dead iff smallest n > nstar
    if ((float)(1021 - t0) <= nstar) {
      const float n0 = (float)(1024 - t0);
      const float n1 = (float)(1023 - t0);
      const float n2 = (float)(1022 - t0);
      const float n3 = (float)(1021 - t0);
      v.x = fast_env(bc * n0) * fast_carrier(fcn, n0) * inv;
      v.y = fast_env(bc * n1) * fast_carrier(fcn, n1) * inv;
      v.z = fast_env(bc * n2) * fast_carrier(fcn, n2) * inv;
      v.w = fast_env(bc * n3) * fast_carrier(fcn, n3) * inv;
    }
    orow[qi] = v;                       // plain cached store, coalesced
  }
}

// ---------------------------------------------------------------------------
extern "C" void kernel_launch(void* const* d_in, const int* in_sizes, int n_in,
                              void* d_out, int out_size, void* d_ws, size_t ws_size,
                              hipStream_t stream) {
  const float* Q  = (const float*)d_in[0];   // [64, 512] f32
  const float* fc = (const float*)d_in[1];   // [512] f32
  float* out      = (float*)d_out;           // [64, 512, 1024] f32
  float* ws       = (float*)d_ws;            // [512*64] per-signal |X|^2 max

  k_maxfft_probe<<<64 * 512 / 4, 256, 0, stream>>>(Q, fc, ws);
  k_write       <<<64 * 512 / 4, 256, 0, stream>>>(Q, fc, ws, out);
}

// Round 8
// 159.827 us; speedup vs baseline: 1.8360x; 1.8360x over previous
//
#include <hip/hip_runtime.h>

// Problem: BATCH=64, NFILT=512, T=1024, FFT over first 512 samples, 257 bins.
//   bc = (fc/Q)*0.5*sqrt(2pi)/FS ; n = t+1
//   y[b,f,t] = exp(-(bc*n)^2) * cos(2pi*fc/FS*n)
//   maxsq[f] = max_{b,k} |DFT_512(y[b,f,0:512])[k]|^2
//   out[b,f,t] = y[b,f,1023-t] * rsqrt(maxsq[f])
//
// R18: grouped-4 Goertzel for full-length signals (bit-identical outputs).
//   Probes: m=22.2us (VALUBusy 69%, Occ 33%, issue-bound+imbalanced),
//   w=17.05us @98% HBM peak (untouchable), C~100-120us fixed.
//   Full-length signals (nstar>=510 <=> jmax=128) have window W<=7 -> <=15
//   distinct bins; 64-lane Goertzel wastes 49 lanes. Here: one wave runs 4
//   FL signals at 16 lanes each (same f, bb=bb0..bb0+3) -> 4x fewer issue
//   cycles on the dominant+tail-critical work. Bit-identical: same jmax=128
//   trips, same bin multiset (clamp dups), same cosf coeffs, same sample
//   values, fmaxf order-invariant. Non-FL signals: exact R12 serial body.
//   k_write: byte-identical R12 (17.05us @ 7.9TB/s proven).
//   Mapping: 2048 blocks; f=blk&511, chunk=blk>>9; wave w owns
//   bb = chunk*16 + w*4 + {0..3}. LDS rows padded to 516 floats so the 4
//   grouped ds_read_b128 addresses land on disjoint banks.
//   Prediction: total 148-156us; absmax EXACTLY 0.0009765625.

#define BCOEF_K 7.8332133582218756e-05f  // 0.5*sqrt(2*pi)/16000
#define INV_FS  6.25e-05f                // 1/16000
#define TWO_PI  6.28318530717958647692f
#define PI_F    3.14159265358979323846f
#define SIGK_K  115.2309f                // sqrt(2)*512/(2*pi)
#define KAPPA   1.3f                     // pruning safety factor
#define FULL_FC 700.0f                   // below this fc, evaluate all 64 b

typedef float vf4 __attribute__((ext_vector_type(4)));

__device__ __forceinline__ float fast_carrier(float fcn, float n) {
  float rev = fcn * n;
  float fr  = rev - floorf(rev);
  return __cosf(TWO_PI * fr);
}
__device__ __forceinline__ float fast_env(float x) { return __expf(-x * x); }

#define ROWF 516  // padded row stride in floats (129 float4s; banks offset 4/row)

// ---------------------------------------------------------------------------
// Kernel 1 (R18): wave owns 4 signals of the same f. FL slots -> grouped
// 16-lane Goertzel; non-FL slots -> exact R12 serial body.
// ---------------------------------------------------------------------------
__global__ __launch_bounds__(256) void k_maxfft2(const float* __restrict__ Q,
                                                 const float* __restrict__ fc,
                                                 float* __restrict__ ws) {
  const int tid   = threadIdx.x;
  const int w     = tid >> 6;            // wave 0..3
  const int lane  = tid & 63;
  const int f     = blockIdx.x & 511;
  const int chunk = blockIdx.x >> 9;     // 0..3
  const int bb0   = chunk * 16 + w * 4;  // this wave's 4 batch rows

  __shared__ __align__(16) float ybuf[4][4][ROWF];  // [wave][slot][padded row]
  float* const rows = &ybuf[w][0][0];

  const float fcv = fc[f];
  const float fcn = fcv * INV_FS;
  const int   kci = (int)(fcn * 512.0f + 0.5f);

  // batch-max Q for the pruning predicate (one reduce per wave, same tree)
  float qq = Q[lane * 512 + f];
  #pragma unroll
  for (int d = 32; d > 0; d >>= 1) qq = fmaxf(qq, __shfl_xor(qq, d));
  const float prthr = KAPPA * fcv * BCOEF_K;

  // per-slot scalars (explicit, no runtime-indexed arrays -> no scratch)
  const float q0 = Q[(bb0 + 0) * 512 + f];
  const float q1 = Q[(bb0 + 1) * 512 + f];
  const float q2 = Q[(bb0 + 2) * 512 + f];
  const float q3 = Q[(bb0 + 3) * 512 + f];
  const float bc0 = (fcv / q0) * BCOEF_K;
  const float bc1 = (fcv / q1) * BCOEF_K;
  const float bc2 = (fcv / q2) * BCOEF_K;
  const float bc3 = (fcv / q3) * BCOEF_K;
  const bool pr0 = (fcv >= FULL_FC && bc0 * qq > prthr);
  const bool pr1 = (fcv >= FULL_FC && bc1 * qq > prthr);
  const bool pr2 = (fcv >= FULL_FC && bc2 * qq > prthr);
  const bool pr3 = (fcv >= FULL_FC && bc3 * qq > prthr);
  const bool fl0 = !pr0 && (4.0f / bc0 >= 510.0f);   // <=> N_eff==512, jmax==128
  const bool fl1 = !pr1 && (4.0f / bc1 >= 510.0f);
  const bool fl2 = !pr2 && (4.0f / bc2 >= 510.0f);
  const bool fl3 = !pr3 && (4.0f / bc3 >= 510.0f);
  const int firstFL = fl0 ? 0 : fl1 ? 1 : fl2 ? 2 : fl3 ? 3 : -1;

  // ---------------- grouped pass: all FL slots at once ----------------
  if (firstFL >= 0) {
    // generate FL rows (full 512 samples, no mask: 8*64 == 512)
    #define GENROW(g, bcg)                                                    \
      {                                                                       \
        float* yr = rows + (g) * ROWF;                                        \
        _Pragma("unroll")                                                     \
        for (int r = 0; r < 8; ++r) {                                         \
          const int idx = (r << 6) + lane;                                    \
          const float n = (float)(idx + 1);                                   \
          yr[idx] = fast_env((bcg) * n) * fast_carrier(fcn, n);               \
        }                                                                     \
      }
    if (fl0) GENROW(0, bc0)
    if (fl1) GENROW(1, bc1)
    if (fl2) GENROW(2, bc2)
    if (fl3) GENROW(3, bc3)
    #undef GENROW
    asm volatile("s_waitcnt lgkmcnt(0)" ::: "memory");

    const int g = lane >> 4;       // signal slot for this lane group
    const int l = lane & 15;       // bin offset within group
    // dead groups shadow firstFL's row (valid data), result discarded
    const bool flg = (g == 0) ? fl0 : (g == 1) ? fl1 : (g == 2) ? fl2 : fl3;
    const int  gsel = flg ? g : firstFL;
    const float bcg = (gsel == 0) ? bc0 : (gsel == 1) ? bc1
                    : (gsel == 2) ? bc2 : bc3;
    const float4* const y4g = (const float4*)(rows + gsel * ROWF);

    // window (W<=7 for FL -> <=15 bins, fits 16 lanes; same multiset as R12)
    const int W    = (int)(2.0f * (bcg * SIGK_K)) + 6;
    const int k_lo = max(0, kci - W);
    const int k_hi = min(256, kci + W);
    const int k    = min(k_lo + l, k_hi);          // dup bins harmless
    const float c  = 2.0f * cosf((float)k * (PI_F / 256.0f));

    float s1 = 0.0f, s2 = 0.0f;
    #pragma unroll 4
    for (int j = 0; j < 128; ++j) {                // jmax==128 for all FL
      const float4 x = y4g[j];
      float s;
      s = fmaf(c, s1, x.x - s2); s2 = s1; s1 = s;
      s = fmaf(c, s1, x.y - s2); s2 = s1; s1 = s;
      s = fmaf(c, s1, x.z - s2); s2 = s1; s1 = s;
      s = fmaf(c, s1, x.w - s2); s2 = s1; s1 = s;
    }
    float mx = fmaxf(0.0f, fmaf(s1, s1, fmaf(s2, s2, -(c * s1 * s2))));
    #pragma unroll
    for (int d = 8; d > 0; d >>= 1) mx = fmaxf(mx, __shfl_xor(mx, d));
    if (l == 0 && flg) ws[f * 64 + (bb0 + g)] = mx;
  }

  // ---------------- serial pass: exact R12 body per non-FL slot ----------
  #define SERIAL(j, bcj, prj, flj)                                            \
    {                                                                         \
      if (prj) {                                                              \
        if (lane == 0) ws[f * 64 + (bb0 + (j))] = 0.0f;                       \
      } else if (!(flj)) {                                                    \
        const float bc = (bcj);                                               \
        const float nstar = 4.0f / bc;                                        \
        const int   N_eff = (nstar >= 510.0f) ? 512 : ((int)nstar + 2);       \
        const int   jmax  = (N_eff + 3) >> 2;                                 \
        const int   n4    = jmax << 2;                                        \
        float* yw = rows + (j) * ROWF;                                        \
        asm volatile("s_waitcnt lgkmcnt(0)" ::: "memory");                    \
        const int nit_g = (n4 + 63) >> 6;                                     \
        for (int r = 0; r < nit_g; ++r) {                                     \
          const int idx = (r << 6) + lane;                                    \
          const float n = (float)(idx + 1);                                   \
          const float v = fast_env(bc * n) * fast_carrier(fcn, n);            \
          if (idx < n4) yw[idx] = v;                                          \
        }                                                                     \
        asm volatile("s_waitcnt lgkmcnt(0)" ::: "memory");                    \
        const int W    = (int)(2.0f * (bc * SIGK_K)) + 6;                     \
        const int k_lo = max(0, kci - W);                                     \
        const int k_hi = min(256, kci + W);                                   \
        const int nit  = ((k_hi - k_lo) >> 6) + 1;                            \
        const float4* y4 = (const float4*)yw;                                 \
        float mx = 0.0f;                                                      \
        for (int it = 0; it < nit; ++it) {                                    \
          const int   k = min(k_lo + (it << 6) + lane, k_hi);                 \
          const float c = 2.0f * cosf((float)k * (PI_F / 256.0f));            \
          float s1 = 0.0f, s2 = 0.0f;                                         \
          _Pragma("unroll 4")                                                 \
          for (int jj = 0; jj < jmax; ++jj) {                                 \
            const float4 x = y4[jj];                                          \
            float s;                                                          \
            s = fmaf(c, s1, x.x - s2); s2 = s1; s1 = s;                       \
            s = fmaf(c, s1, x.y - s2); s2 = s1; s1 = s;                       \
            s = fmaf(c, s1, x.z - s2); s2 = s1; s1 = s;                       \
            s = fmaf(c, s1, x.w - s2); s2 = s1; s1 = s;                       \
          }                                                                   \
          mx = fmaxf(mx, fmaf(s1, s1, fmaf(s2, s2, -(c * s1 * s2))));         \
        }                                                                     \
        _Pragma("unroll")                                                     \
        for (int d = 32; d > 0; d >>= 1) mx = fmaxf(mx, __shfl_xor(mx, d));   \
        if (lane == 0) ws[f * 64 + (bb0 + (j))] = mx;                         \
      }                                                                       \
    }
  SERIAL(0, bc0, pr0, fl0)
  SERIAL(1, bc1, pr1, fl1)
  SERIAL(2, bc2, pr2, fl2)
  SERIAL(3, bc3, pr3, fl3)
  #undef SERIAL
}

// ---------------------------------------------------------------------------
// Kernel 2: EXACT R12 k_write (17.05us, 7.9 TB/s = 98% peak, proven R16).
// ---------------------------------------------------------------------------
__global__ __launch_bounds__(256) void k_write(const float* __restrict__ Q,
                                               const float* __restrict__ fc,
                                               const float* __restrict__ ws,
                                               float* __restrict__ out) {
  const int tid  = threadIdx.x;
  const int w    = tid >> 6;            // wave = row within the 4-row block
  const int lane = tid & 63;
  const int sig  = blockIdx.x * 4 + w;  // bb*512 + f
  const int f    = sig & 511;
  const int bb   = sig >> 9;

  float mx = ws[f * 64 + lane];         // 64 consecutive floats, coalesced
  #pragma unroll
  for (int d = 32; d > 0; d >>= 1) mx = fmaxf(mx, __shfl_xor(mx, d));
  const float inv = rsqrtf(mx);

  const float fcv = fc[f];
  const float q   = Q[bb * 512 + f];
  const float bc  = (fcv / q) * BCOEF_K;
  const float fcn = fcv * INV_FS;
  const float nstar = 4.0f / bc;

  vf4* __restrict__ orow = (vf4*)out + (size_t)sig * 256;
  #pragma unroll
  for (int r = 0; r < 4; ++r) {
    const int qi = (r << 6) + lane;     // quad index within row, 0..255
    const int t0 = qi << 2;             // t of first element in quad
    vf4 v = {0.0f, 0.0f, 0.0f, 0.0f};
    // quad covers n = 1021-t0 .. 1024-t0; all dead iff smallest n > nstar
    if ((float)(1021 - t0) <= nstar) {
      const float n0 = (float)(1024 - t0);
      const float n1 = (float)(1023 - t0);
      const float n2 = (float)(1022 - t0);
      const float n3 = (float)(1021 - t0);
      v.x = fast_env(bc * n0) * fast_carrier(fcn, n0) * inv;
      v.y = fast_env(bc * n1) * fast_carrier(fcn, n1) * inv;
      v.z = fast_env(bc * n2) * fast_carrier(fcn, n2) * inv;
      v.w = fast_env(bc * n3) * fast_carrier(fcn, n3) * inv;
    }
    orow[qi] = v;                       // plain cached store, coalesced
  }
}

// ---------------------------------------------------------------------------
extern "C" void kernel_launch(void* const* d_in, const int* in_sizes, int n_in,
                              void* d_out, int out_size, void* d_ws, size_t ws_size,
                              hipStream_t stream) {
  const float* Q  = (const float*)d_in[0];   // [64, 512] f32
  const float* fc = (const float*)d_in[1];   // [512] f32
  float* out      = (float*)d_out;           // [64, 512, 1024] f32
  float* ws       = (float*)d_ws;            // [512*64] per-signal |X|^2 max

  k_maxfft2<<<2048,       256, 0, stream>>>(Q, fc, ws);
  k_write  <<<64 * 512 / 4, 256, 0, stream>>>(Q, fc, ws, out);
}

// Round 9
// 151.328 us; speedup vs baseline: 1.9391x; 1.0562x over previous
//
#include <hip/hip_runtime.h>

// Problem: BATCH=64, NFILT=512, T=1024, FFT over first 512 samples, 257 bins.
//   bc = (fc/Q)*0.5*sqrt(2pi)/FS ; n = t+1
//   y[b,f,t] = exp(-(bc*n)^2) * cos(2pi*fc/FS*n)
//   maxsq[f] = max_{b,k} |DFT_512(y[b,f,0:512])[k]|^2
//   out[b,f,t] = y[b,f,1023-t] * rsqrt(maxsq[f])
//
// R19: scheduling-only attack on k_maxfft's measured 31% idle (R17 probe:
//   m=22.2us, VALUBusy 69% => ~15.5us issue + ~6.5us idle/tail).
//   R18 post-mortem: FL-grouping's true upside was 1.3us (4.1M of 37M busy
//   cycles), prediction arithmetic was wrong; measured neutral. Reverted.
//   Changes vs R12 (ALL bit-identical math; absmax must stay 0.0009765625):
//   1. f-major mapping: f = blk>>4, bb = (blk&15)*4 + w. Heavy low-f
//      filters launch FIRST; light/pruned high-f work backfills the
//      dispatch tail (makespan/LPT heuristic). R12 had f = sig&511, which
//      put f=0..3 (heaviest) in the LAST blocks.
//   2. Block-uniform f => pruning column gather Q[lane*512+f] done once
//      per block by wave 0 into LDS (was per-wave): 4x less gather
//      traffic (134MB -> 33MB L2) and latency. Same values, same shfl
//      reduce tree => bit-identical qq.
//   k_write: byte-identical R12 (17.05us @ 7.9TB/s = 98% peak, proven R16).
//   Prediction: m -> 16-18us, total 152-156us. If >=159, tail theory wrong.

#define BCOEF_K 7.8332133582218756e-05f  // 0.5*sqrt(2*pi)/16000
#define INV_FS  6.25e-05f                // 1/16000
#define TWO_PI  6.28318530717958647692f
#define PI_F    3.14159265358979323846f
#define SIGK_K  115.2309f                // sqrt(2)*512/(2*pi)
#define KAPPA   1.3f                     // pruning safety factor
#define FULL_FC 700.0f                   // below this fc, evaluate all 64 b

typedef float vf4 __attribute__((ext_vector_type(4)));

__device__ __forceinline__ float fast_carrier(float fcn, float n) {
  float rev = fcn * n;
  float fr  = rev - floorf(rev);
  return __cosf(TWO_PI * fr);
}
__device__ __forceinline__ float fast_env(float x) { return __expf(-x * x); }

// ---------------------------------------------------------------------------
// Kernel 1 (R19): f-major block mapping; 4 waves of a block share filter f
// and handle bb = (blk&15)*4 + w. Body from the pruning predicate onward is
// exactly R12's (bit-identical per-signal arithmetic).
// ---------------------------------------------------------------------------
__global__ __launch_bounds__(256) void k_maxfft(const float* __restrict__ Q,
                                                const float* __restrict__ fc,
                                                float* __restrict__ ws) {
  const int tid  = threadIdx.x;
  const int w    = tid >> 6;           // wave 0..3
  const int lane = tid & 63;
  const int f    = blockIdx.x >> 4;          // block-uniform filter
  const int bb   = ((blockIdx.x & 15) << 2) + w;

  __shared__ __align__(16) float ybuf[4][512];
  __shared__ float qcol[64];

  // one gather per block: wave 0 loads the Q column for f
  if (tid < 64) qcol[tid] = Q[tid * 512 + f];
  __syncthreads();

  const float fcv = fc[f];
  const float q   = qcol[bb];
  const float bc  = (fcv / q) * BCOEF_K;
  const float fcn = fcv * INV_FS;

  // --- pruning: candidate iff bc <= KAPPA * bc_min(batch) or low-fc ---
  float qq = qcol[lane];               // same values as R12's gather
  #pragma unroll
  for (int d = 32; d > 0; d >>= 1) qq = fmaxf(qq, __shfl_xor(qq, d));
  if (fcv >= FULL_FC && bc * qq > KAPPA * fcv * BCOEF_K) {
    if (lane == 0) ws[f * 64 + bb] = 0.0f;   // provably below batch max
    return;                                   // wave-uniform exit (no more barriers)
  }

  // --- effective length: env < e^-16 beyond nstar = 4/bc (wave-uniform) ---
  const float nstar = 4.0f / bc;
  const int   N_eff = (nstar >= 510.0f) ? 512 : ((int)nstar + 2);
  const int   jmax  = (N_eff + 3) >> 2;      // float4 groups Goertzel reads
  const int   n4    = jmax << 2;             // samples to generate

  // --- lane-strided generation: lane writes samples lane, lane+64, ... ---
  float* yw = &ybuf[w][0];
  const int nit_g = (n4 + 63) >> 6;          // 1..8, wave-uniform
  for (int r = 0; r < nit_g; ++r) {
    const int idx = (r << 6) + lane;         // t index; n = idx+1
    const float n = (float)(idx + 1);
    const float v = fast_env(bc * n) * fast_carrier(fcn, n);
    if (idx < n4) yw[idx] = v;               // masked tail store
  }
  // Wave-local write->read ordering (row is private to this wave).
  asm volatile("s_waitcnt lgkmcnt(0)" ::: "memory");

  // --- spectral-peak window (wave-uniform) ---
  const int kci  = (int)(fcn * 512.0f + 0.5f);
  const int W    = (int)(2.0f * (bc * SIGK_K)) + 6;
  const int k_lo = max(0, kci - W);
  const int k_hi = min(256, kci + W);
  const int nit  = ((k_hi - k_lo) >> 6) + 1;  // 1..5 iterations

  const float4* y4 = (const float4*)yw;      // wave-uniform broadcasts
  float mx = 0.0f;
  for (int it = 0; it < nit; ++it) {         // wave-uniform trip count
    const int   k = min(k_lo + (it << 6) + lane, k_hi);  // dup bins harmless
    const float c = 2.0f * cosf((float)k * (PI_F / 256.0f));
    float s1 = 0.0f, s2 = 0.0f;
    #pragma unroll 4
    for (int j = 0; j < jmax; ++j) {         // wave-uniform trip count
      const float4 x = y4[j];
      float s;
      s = fmaf(c, s1, x.x - s2); s2 = s1; s1 = s;
      s = fmaf(c, s1, x.y - s2); s2 = s1; s1 = s;
      s = fmaf(c, s1, x.z - s2); s2 = s1; s1 = s;
      s = fmaf(c, s1, x.w - s2); s2 = s1; s1 = s;
    }
    mx = fmaxf(mx, fmaf(s1, s1, fmaf(s2, s2, -(c * s1 * s2))));
  }

  #pragma unroll
  for (int d = 32; d > 0; d >>= 1) mx = fmaxf(mx, __shfl_xor(mx, d));
  if (lane == 0) ws[f * 64 + bb] = mx;       // per-signal result, no atomic
}

// ---------------------------------------------------------------------------
// Kernel 2: EXACT R12 k_write (17.05us, 7.9 TB/s = 98% peak, proven R16).
// ---------------------------------------------------------------------------
__global__ __launch_bounds__(256) void k_write(const float* __restrict__ Q,
                                               const float* __restrict__ fc,
                                               const float* __restrict__ ws,
                                               float* __restrict__ out) {
  const int tid  = threadIdx.x;
  const int w    = tid >> 6;            // wave = row within the 4-row block
  const int lane = tid & 63;
  const int sig  = blockIdx.x * 4 + w;  // bb*512 + f
  const int f    = sig & 511;
  const int bb   = sig >> 9;

  float mx = ws[f * 64 + lane];         // 64 consecutive floats, coalesced
  #pragma unroll
  for (int d = 32; d > 0; d >>= 1) mx = fmaxf(mx, __shfl_xor(mx, d));
  const float inv = rsqrtf(mx);

  const float fcv = fc[f];
  const float q   = Q[bb * 512 + f];
  const float bc  = (fcv / q) * BCOEF_K;
  const float fcn = fcv * INV_FS;
  const float nstar = 4.0f / bc;

  vf4* __restrict__ orow = (vf4*)out + (size_t)sig * 256;
  #pragma unroll
  for (int r = 0; r < 4; ++r) {
    const int qi = (r << 6) + lane;     // quad index within row, 0..255
    const int t0 = qi << 2;             // t of first element in quad
    vf4 v = {0.0f, 0.0f, 0.0f, 0.0f};
    // quad covers n = 1021-t0 .. 1024-t0; all dead iff smallest n > nstar
    if ((float)(1021 - t0) <= nstar) {
      const float n0 = (float)(1024 - t0);
      const float n1 = (float)(1023 - t0);
      const float n2 = (float)(1022 - t0);
      const float n3 = (float)(1021 - t0);
      v.x = fast_env(bc * n0) * fast_carrier(fcn, n0) * inv;
      v.y = fast_env(bc * n1) * fast_carrier(fcn, n1) * inv;
      v.z = fast_env(bc * n2) * fast_carrier(fcn, n2) * inv;
      v.w = fast_env(bc * n3) * fast_carrier(fcn, n3) * inv;
    }
    orow[qi] = v;                       // plain cached store, coalesced
  }
}

// ---------------------------------------------------------------------------
extern "C" void kernel_launch(void* const* d_in, const int* in_sizes, int n_in,
                              void* d_out, int out_size, void* d_ws, size_t ws_size,
                              hipStream_t stream) {
  const float* Q  = (const float*)d_in[0];   // [64, 512] f32
  const float* fc = (const float*)d_in[1];   // [512] f32
  float* out      = (float*)d_out;           // [64, 512, 1024] f32
  float* ws       = (float*)d_ws;            // [512*64] per-signal |X|^2 max

  k_maxfft<<<64 * 512 / 4, 256, 0, stream>>>(Q, fc, ws);
  k_write <<<64 * 512 / 4, 256, 0, stream>>>(Q, fc, ws, out);
}